// Round 1
// baseline (768.559 us; speedup 1.0000x reference)
//
#include <hip/hip_runtime.h>
#include <cfloat>
#include <cstddef>

#define HW 9216
#define MROWS 2304
#define NB 4

// ws layout (bytes)
constexpr size_t OFF_INVNF = 0;                      // 4*9216 f32
constexpr size_t OFF_ARRO  = OFF_INVNF + 147456;     // 4*9216 f32 (signed: neg => masked)
constexpr size_t OFF_ARRF  = OFF_ARRO  + 147456;
constexpr size_t OFF_PVAL  = OFF_ARRF  + 147456;     // 8 bb * 4 strips * 2304 f32
constexpr size_t OFF_PIDX  = OFF_PVAL  + 294912;     // same, i32
constexpr size_t OFF_ORI   = OFF_PIDX  + 294912;     // 4*2304 i32
constexpr size_t OFF_CFO   = OFF_ORI   + 36864;      // 4*9216 i32
constexpr size_t OFF_CFF   = OFF_CFO   + 147456;
constexpr size_t OFF_SO    = OFF_CFF   + 147456;     // 4*64 f32
constexpr size_t OFF_SF    = OFF_SO    + 1024;

// K1: per-pixel inverse norms (+mask sign), zero scatter targets
__global__ __launch_bounds__(256) void norm_kernel(
    const float* __restrict__ x, const float* __restrict__ flip,
    float* __restrict__ invnf, float* __restrict__ arro, float* __restrict__ arrf,
    int* __restrict__ cfo, int* __restrict__ cff,
    float* __restrict__ So, float* __restrict__ Sf)
{
    int b = blockIdx.y;
    int pix = blockIdx.x * 256 + threadIdx.x;   // gridDim.x = 36 -> exact
    const float* xb = x + (size_t)b * 128 * HW;
    const float* fb = flip + (size_t)b * 64 * HW;
    float nf = 0.f, nl = 0.f, nfl = 0.f;
    #pragma unroll 8
    for (int c = 0; c < 64; ++c) {
        float a = xb[(size_t)c * HW + pix];        nf  += a * a;
        float l = xb[(size_t)(64 + c) * HW + pix]; nl  += l * l;
        float f = fb[(size_t)c * HW + pix];        nfl += f * f;
    }
    int r = pix / 96, cc = pix % 96;
    bool in_o = (r >= 24 && r < 72 && cc >= 20 && cc < 68);
    bool in_f = (r >= 24 && r < 72 && cc >= 28 && cc < 76);
    float il  = 1.f / sqrtf(nl);
    float ifl = 1.f / sqrtf(nfl);
    invnf[b * HW + pix] = 1.f / sqrtf(nf);
    arro[b * HW + pix] = in_o ? -il  : il;
    arrf[b * HW + pix] = in_f ? -ifl : ifl;
    cfo[b * HW + pix] = 0;
    cff[b * HW + pix] = 0;
    if (pix < 64) { So[b * 64 + pix] = 0.f; Sf[b * 64 + pix] = 0.f; }
}

// K2: masked argmax GEMM. grid: x=72 row-blocks(32 rows), y=4 col strips(2304), z=8 (b*2+branch)
__global__ __launch_bounds__(256) void argmax_kernel(
    const float* __restrict__ x, const float* __restrict__ flip,
    const float* __restrict__ arro, const float* __restrict__ arrf,
    float* __restrict__ pval, int* __restrict__ pidx)
{
    int rb = blockIdx.x, strip = blockIdx.y, bb = blockIdx.z;
    int b = bb >> 1, br = bb & 1;
    const float* A  = x + (size_t)b * 128 * HW;                       // former
    const float* Bm = br ? (flip + (size_t)b * 64 * HW)
                         : (x + (size_t)b * 128 * HW + (size_t)64 * HW);
    const float* inv = (br ? arrf : arro) + (size_t)b * HW;
    int cbase = br ? 28 : 20;
    int mbase = rb * 32;
    int jstrip = strip * 2304;

    __shared__ float As[64][32];     // [k][row]
    __shared__ float Bs[64][128];    // [k][col]

    int t = threadIdx.x;
    // load A tile once (32 rows x 64 k)
    #pragma unroll
    for (int it = 0; it < 8; ++it) {
        int idx = t + it * 256;          // 0..2047
        int k = idx >> 5, rr = idx & 31;
        int m = mbase + rr;
        int pix = (24 + m / 48) * 96 + cbase + (m % 48);
        As[k][rr] = A[(size_t)k * HW + pix];
    }

    int cg = t & 31, rg = t >> 5;
    int c0 = cg * 4, r0 = rg * 4;
    float rv[4]; int rix[4];
    #pragma unroll
    for (int i = 0; i < 4; ++i) { rv[i] = -FLT_MAX; rix[i] = 0x7fffffff; }

    for (int tile = 0; tile < 18; ++tile) {
        int jbase = jstrip + tile * 128;
        __syncthreads();
        #pragma unroll
        for (int it = 0; it < 8; ++it) {
            int idx = t + it * 256;              // 2048 float4s
            int k = idx >> 5, c4 = idx & 31;
            const float4* src = reinterpret_cast<const float4*>(Bm + (size_t)k * HW + jbase);
            reinterpret_cast<float4*>(&Bs[k][0])[c4] = src[c4];
        }
        __syncthreads();

        float acc[4][4] = {{0.f}};
        #pragma unroll 16
        for (int k = 0; k < 64; ++k) {
            float4 a = *reinterpret_cast<const float4*>(&As[k][r0]);
            float4 bv = *reinterpret_cast<const float4*>(&Bs[k][c0]);
            acc[0][0] += a.x * bv.x; acc[0][1] += a.x * bv.y; acc[0][2] += a.x * bv.z; acc[0][3] += a.x * bv.w;
            acc[1][0] += a.y * bv.x; acc[1][1] += a.y * bv.y; acc[1][2] += a.y * bv.z; acc[1][3] += a.y * bv.w;
            acc[2][0] += a.z * bv.x; acc[2][1] += a.z * bv.y; acc[2][2] += a.z * bv.z; acc[2][3] += a.z * bv.w;
            acc[3][0] += a.w * bv.x; acc[3][1] += a.w * bv.y; acc[3][2] += a.w * bv.z; acc[3][3] += a.w * bv.w;
        }
        #pragma unroll
        for (int ci = 0; ci < 4; ++ci) {
            int j = jbase + c0 + ci;
            float iv = inv[j];
            bool masked = iv < 0.f;
            #pragma unroll
            for (int rr = 0; rr < 4; ++rr) {
                float s = masked ? -FLT_MAX : acc[rr][ci] * iv;
                if (s > rv[rr]) { rv[rr] = s; rix[rr] = j; }
            }
        }
    }

    __syncthreads();
    float* redv = &Bs[0][0];                       // 32*32 floats
    int*   redi = reinterpret_cast<int*>(&Bs[0][0]) + 1024;
    #pragma unroll
    for (int rr = 0; rr < 4; ++rr) {
        redv[(r0 + rr) * 32 + cg] = rv[rr];
        redi[(r0 + rr) * 32 + cg] = rix[rr];
    }
    __syncthreads();
    if (t < 32) {
        float bv = -FLT_MAX; int bi = 0x7fffffff;
        for (int c = 0; c < 32; ++c) {
            float v = redv[t * 32 + c]; int ii = redi[t * 32 + c];
            if (v > bv || (v == bv && ii < bi)) { bv = v; bi = ii; }
        }
        int m = mbase + t;
        pval[((size_t)bb * 4 + strip) * MROWS + m] = bv;
        pidx[((size_t)bb * 4 + strip) * MROWS + m] = bi;
    }
}

// K3: merge 4 strips per (bb,m), compute ori flag, scatter column flags
__global__ __launch_bounds__(256) void merge_kernel(
    const float* __restrict__ pval, const int* __restrict__ pidx,
    const float* __restrict__ invnf, int* __restrict__ ori,
    int* __restrict__ cfo, int* __restrict__ cff)
{
    int gid = blockIdx.x * 256 + threadIdx.x;      // 36 blocks -> 9216 = 4*2304
    int b = gid / MROWS, m = gid % MROWS;
    float bv[2]; int bi[2];
    #pragma unroll
    for (int br = 0; br < 2; ++br) {
        int bb = b * 2 + br;
        float v = -FLT_MAX; int id = 0x7fffffff;
        for (int s = 0; s < 4; ++s) {
            float pv = pval[((size_t)bb * 4 + s) * MROWS + m];
            int   pi = pidx[((size_t)bb * 4 + s) * MROWS + m];
            if (pv > v || (pv == v && pi < id)) { v = pv; id = pi; }
        }
        int cbase = br ? 28 : 20;
        int pix = (24 + m / 48) * 96 + cbase + (m % 48);
        v *= invnf[b * HW + pix];
        bv[br] = v; bi[br] = id;
    }
    bool o = bv[0] >= bv[1];
    ori[gid] = o ? 1 : 0;
    cfo[b * HW + bi[0]] = 1;
    cff[b * HW + bi[1]] = 1;
}

// K4: S vectors = sum of flagged columns
__global__ __launch_bounds__(256) void ssum_kernel(
    const float* __restrict__ x, const float* __restrict__ flip,
    const int* __restrict__ cfo, const int* __restrict__ cff,
    float* __restrict__ So, float* __restrict__ Sf)
{
    int blk = blockIdx.x;                  // 8 = b*2+br
    int b = blk >> 1, br = blk & 1;
    const float* Bm = br ? (flip + (size_t)b * 64 * HW)
                         : (x + (size_t)b * 128 * HW + (size_t)64 * HW);
    const int* cf = (br ? cff : cfo) + (size_t)b * HW;
    float* S = (br ? Sf : So) + b * 64;
    float acc[64];
    #pragma unroll
    for (int c = 0; c < 64; ++c) acc[c] = 0.f;
    for (int j = threadIdx.x; j < HW; j += 256) {
        if (cf[j]) {
            #pragma unroll
            for (int c = 0; c < 64; ++c) acc[c] += Bm[(size_t)c * HW + j];
        }
    }
    #pragma unroll
    for (int c = 0; c < 64; ++c) {
        float v = acc[c];
        for (int off = 32; off > 0; off >>= 1) v += __shfl_down(v, off, 64);
        if ((threadIdx.x & 63) == 0) atomicAdd(&S[c], v);
    }
}

// K5: assemble output [4][192][9216]
__global__ __launch_bounds__(256) void assemble_kernel(
    const float* __restrict__ x, const int* __restrict__ ori,
    const float* __restrict__ So, const float* __restrict__ Sf,
    float* __restrict__ out)
{
    int idx = blockIdx.x * 256 + threadIdx.x;      // float4 index; grid covers exactly
    const int PER_B4 = 192 * (HW / 4);             // 442368
    int b = idx / PER_B4;
    int rem = idx - b * PER_B4;
    int ch = rem / (HW / 4);
    int p4 = rem % (HW / 4);
    float4 v;
    if (ch < 128) {
        v = reinterpret_cast<const float4*>(x + ((size_t)b * 128 + ch) * HW)[p4];
    } else {
        int c = ch - 128;
        int pix = p4 * 4;
        int r = pix / 96, cc = pix % 96;           // 4 consecutive pixels share the row (96%4==0)
        float so = So[b * 64 + c], sf = Sf[b * 64 + c];
        float vals[4];
        #pragma unroll
        for (int i = 0; i < 4; ++i) {
            int ccc = cc + i;
            if (r >= 24 && r < 72 && ccc >= 20 && ccc < 68) {
                int m = (r - 24) * 48 + (ccc - 20);
                vals[i] = ori[b * MROWS + m] ? so : sf;
            } else vals[i] = 0.f;
        }
        v = make_float4(vals[0], vals[1], vals[2], vals[3]);
    }
    reinterpret_cast<float4*>(out)[idx] = v;
}

extern "C" void kernel_launch(void* const* d_in, const int* in_sizes, int n_in,
                              void* d_out, int out_size, void* d_ws, size_t ws_size,
                              hipStream_t stream) {
    const float* x    = (const float*)d_in[0];   // [4,128,9216]
    const float* flip = (const float*)d_in[1];   // [4,64,9216]
    char* w = (char*)d_ws;
    float* invnf = (float*)(w + OFF_INVNF);
    float* arro  = (float*)(w + OFF_ARRO);
    float* arrf  = (float*)(w + OFF_ARRF);
    float* pval  = (float*)(w + OFF_PVAL);
    int*   pidx  = (int*)  (w + OFF_PIDX);
    int*   ori   = (int*)  (w + OFF_ORI);
    int*   cfo   = (int*)  (w + OFF_CFO);
    int*   cff   = (int*)  (w + OFF_CFF);
    float* So    = (float*)(w + OFF_SO);
    float* Sf    = (float*)(w + OFF_SF);
    float* out   = (float*)d_out;

    norm_kernel<<<dim3(36, 4), 256, 0, stream>>>(x, flip, invnf, arro, arrf, cfo, cff, So, Sf);
    argmax_kernel<<<dim3(72, 4, 8), 256, 0, stream>>>(x, flip, arro, arrf, pval, pidx);
    merge_kernel<<<36, 256, 0, stream>>>(pval, pidx, invnf, ori, cfo, cff);
    ssum_kernel<<<8, 256, 0, stream>>>(x, flip, cfo, cff, So, Sf);
    assemble_kernel<<<6912, 256, 0, stream>>>(x, ori, So, Sf, out);
}

// Round 2
// 443.391 us; speedup vs baseline: 1.7334x; 1.7334x over previous
//
#include <hip/hip_runtime.h>
#include <cfloat>
#include <cstddef>

#define HW 9216
#define MROWS 2304
#define NB 4

// ws layout (bytes)
constexpr size_t OFF_INVNF = 0;                      // 4*9216 f32
constexpr size_t OFF_ARRO  = OFF_INVNF + 147456;     // 4*9216 f32 (signed: neg => masked)
constexpr size_t OFF_ARRF  = OFF_ARRO  + 147456;
constexpr size_t OFF_PVAL  = OFF_ARRF  + 147456;     // 8 bb * 4 strips * 2304 f32
constexpr size_t OFF_PIDX  = OFF_PVAL  + 294912;     // same, i32
constexpr size_t OFF_ORI   = OFF_PIDX  + 294912;     // 4*2304 i32
constexpr size_t OFF_CFO   = OFF_ORI   + 36864;      // 4*9216 i32
constexpr size_t OFF_CFF   = OFF_CFO   + 147456;
constexpr size_t OFF_SO    = OFF_CFF   + 147456;     // 4*64 f32
constexpr size_t OFF_SF    = OFF_SO    + 1024;

// K1: per-pixel inverse norms (+mask sign), zero scatter targets
__global__ __launch_bounds__(256) void norm_kernel(
    const float* __restrict__ x, const float* __restrict__ flip,
    float* __restrict__ invnf, float* __restrict__ arro, float* __restrict__ arrf,
    int* __restrict__ cfo, int* __restrict__ cff,
    float* __restrict__ So, float* __restrict__ Sf)
{
    int b = blockIdx.y;
    int pix = blockIdx.x * 256 + threadIdx.x;   // gridDim.x = 36 -> exact
    const float* xb = x + (size_t)b * 128 * HW;
    const float* fb = flip + (size_t)b * 64 * HW;
    float nf = 0.f, nl = 0.f, nfl = 0.f;
    #pragma unroll 8
    for (int c = 0; c < 64; ++c) {
        float a = xb[(size_t)c * HW + pix];        nf  += a * a;
        float l = xb[(size_t)(64 + c) * HW + pix]; nl  += l * l;
        float f = fb[(size_t)c * HW + pix];        nfl += f * f;
    }
    int r = pix / 96, cc = pix % 96;
    bool in_o = (r >= 24 && r < 72 && cc >= 20 && cc < 68);
    bool in_f = (r >= 24 && r < 72 && cc >= 28 && cc < 76);
    float il  = 1.f / sqrtf(nl);
    float ifl = 1.f / sqrtf(nfl);
    invnf[b * HW + pix] = 1.f / sqrtf(nf);
    arro[b * HW + pix] = in_o ? -il  : il;
    arrf[b * HW + pix] = in_f ? -ifl : ifl;
    cfo[b * HW + pix] = 0;
    cff[b * HW + pix] = 0;
    if (pix < 64) { So[b * 64 + pix] = 0.f; Sf[b * 64 + pix] = 0.f; }
}

// K2: masked argmax GEMM. grid: x=72 row-blocks(32 rows), y=4 col strips(2304), z=8 (b*2+branch)
__global__ __launch_bounds__(256) void argmax_kernel(
    const float* __restrict__ x, const float* __restrict__ flip,
    const float* __restrict__ arro, const float* __restrict__ arrf,
    float* __restrict__ pval, int* __restrict__ pidx)
{
    int rb = blockIdx.x, strip = blockIdx.y, bb = blockIdx.z;
    int b = bb >> 1, br = bb & 1;
    const float* A  = x + (size_t)b * 128 * HW;                       // former
    const float* Bm = br ? (flip + (size_t)b * 64 * HW)
                         : (x + (size_t)b * 128 * HW + (size_t)64 * HW);
    const float* inv = (br ? arrf : arro) + (size_t)b * HW;
    int cbase = br ? 28 : 20;
    int mbase = rb * 32;
    int jstrip = strip * 2304;

    __shared__ float As[64][32];     // [k][row]
    __shared__ float Bs[64][128];    // [k][col]

    int t = threadIdx.x;
    // load A tile once (32 rows x 64 k)
    #pragma unroll
    for (int it = 0; it < 8; ++it) {
        int idx = t + it * 256;          // 0..2047
        int k = idx >> 5, rr = idx & 31;
        int m = mbase + rr;
        int pix = (24 + m / 48) * 96 + cbase + (m % 48);
        As[k][rr] = A[(size_t)k * HW + pix];
    }

    int cg = t & 31, rg = t >> 5;
    int c0 = cg * 4, r0 = rg * 4;
    float rv[4]; int rix[4];
    #pragma unroll
    for (int i = 0; i < 4; ++i) { rv[i] = -FLT_MAX; rix[i] = 0x7fffffff; }

    for (int tile = 0; tile < 18; ++tile) {
        int jbase = jstrip + tile * 128;
        __syncthreads();
        #pragma unroll
        for (int it = 0; it < 8; ++it) {
            int idx = t + it * 256;              // 2048 float4s
            int k = idx >> 5, c4 = idx & 31;
            const float4* src = reinterpret_cast<const float4*>(Bm + (size_t)k * HW + jbase);
            reinterpret_cast<float4*>(&Bs[k][0])[c4] = src[c4];
        }
        __syncthreads();

        float acc[4][4] = {{0.f}};
        #pragma unroll 16
        for (int k = 0; k < 64; ++k) {
            float4 a = *reinterpret_cast<const float4*>(&As[k][r0]);
            float4 bv = *reinterpret_cast<const float4*>(&Bs[k][c0]);
            acc[0][0] += a.x * bv.x; acc[0][1] += a.x * bv.y; acc[0][2] += a.x * bv.z; acc[0][3] += a.x * bv.w;
            acc[1][0] += a.y * bv.x; acc[1][1] += a.y * bv.y; acc[1][2] += a.y * bv.z; acc[1][3] += a.y * bv.w;
            acc[2][0] += a.z * bv.x; acc[2][1] += a.z * bv.y; acc[2][2] += a.z * bv.z; acc[2][3] += a.z * bv.w;
            acc[3][0] += a.w * bv.x; acc[3][1] += a.w * bv.y; acc[3][2] += a.w * bv.z; acc[3][3] += a.w * bv.w;
        }
        #pragma unroll
        for (int ci = 0; ci < 4; ++ci) {
            int j = jbase + c0 + ci;
            float iv = inv[j];
            bool masked = iv < 0.f;
            #pragma unroll
            for (int rr = 0; rr < 4; ++rr) {
                float s = masked ? -FLT_MAX : acc[rr][ci] * iv;
                if (s > rv[rr]) { rv[rr] = s; rix[rr] = j; }
            }
        }
    }

    __syncthreads();
    float* redv = &Bs[0][0];                       // 32*32 floats
    int*   redi = reinterpret_cast<int*>(&Bs[0][0]) + 1024;
    #pragma unroll
    for (int rr = 0; rr < 4; ++rr) {
        redv[(r0 + rr) * 32 + cg] = rv[rr];
        redi[(r0 + rr) * 32 + cg] = rix[rr];
    }
    __syncthreads();
    if (t < 32) {
        float bv = -FLT_MAX; int bi = 0x7fffffff;
        for (int c = 0; c < 32; ++c) {
            float v = redv[t * 32 + c]; int ii = redi[t * 32 + c];
            if (v > bv || (v == bv && ii < bi)) { bv = v; bi = ii; }
        }
        int m = mbase + t;
        pval[((size_t)bb * 4 + strip) * MROWS + m] = bv;
        pidx[((size_t)bb * 4 + strip) * MROWS + m] = bi;
    }
}

// K3: merge 4 strips per (bb,m), compute ori flag, scatter column flags
__global__ __launch_bounds__(256) void merge_kernel(
    const float* __restrict__ pval, const int* __restrict__ pidx,
    const float* __restrict__ invnf, int* __restrict__ ori,
    int* __restrict__ cfo, int* __restrict__ cff)
{
    int gid = blockIdx.x * 256 + threadIdx.x;      // 36 blocks -> 9216 = 4*2304
    int b = gid / MROWS, m = gid % MROWS;
    float bv[2]; int bi[2];
    #pragma unroll
    for (int br = 0; br < 2; ++br) {
        int bb = b * 2 + br;
        float v = -FLT_MAX; int id = 0x7fffffff;
        for (int s = 0; s < 4; ++s) {
            float pv = pval[((size_t)bb * 4 + s) * MROWS + m];
            int   pi = pidx[((size_t)bb * 4 + s) * MROWS + m];
            if (pv > v || (pv == v && pi < id)) { v = pv; id = pi; }
        }
        int cbase = br ? 28 : 20;
        int pix = (24 + m / 48) * 96 + cbase + (m % 48);
        v *= invnf[b * HW + pix];
        bv[br] = v; bi[br] = id;
    }
    bool o = bv[0] >= bv[1];
    ori[gid] = o ? 1 : 0;
    cfo[b * HW + bi[0]] = 1;
    cff[b * HW + bi[1]] = 1;
}

// K4: S[c] = sum over flagged columns j of Bm[c][j].
// One block per (bb, c): 512 blocks, scalar accumulator per thread (no spill),
// coalesced loads, block-level reduce, single store (no atomics).
__global__ __launch_bounds__(256) void ssum_kernel(
    const float* __restrict__ x, const float* __restrict__ flip,
    const int* __restrict__ cfo, const int* __restrict__ cff,
    float* __restrict__ So, float* __restrict__ Sf)
{
    int blk = blockIdx.x;                  // 8 = b*2+br
    int c   = blockIdx.y;                  // 64 channels
    int b = blk >> 1, br = blk & 1;
    const float* Bm = br ? (flip + (size_t)b * 64 * HW)
                         : (x + (size_t)b * 128 * HW + (size_t)64 * HW);
    const int* cf = (br ? cff : cfo) + (size_t)b * HW;
    float* S = (br ? Sf : So) + b * 64;

    const float* row = Bm + (size_t)c * HW;
    float acc = 0.f;
    for (int j = threadIdx.x; j < HW; j += 256) {
        if (cf[j]) acc += row[j];
    }
    // wave reduce (64 lanes)
    for (int off = 32; off > 0; off >>= 1) acc += __shfl_down(acc, off, 64);
    __shared__ float part[4];
    int lane = threadIdx.x & 63, wv = threadIdx.x >> 6;
    if (lane == 0) part[wv] = acc;
    __syncthreads();
    if (threadIdx.x == 0) {
        S[c] = part[0] + part[1] + part[2] + part[3];
    }
}

// K5: assemble output [4][192][9216]
__global__ __launch_bounds__(256) void assemble_kernel(
    const float* __restrict__ x, const int* __restrict__ ori,
    const float* __restrict__ So, const float* __restrict__ Sf,
    float* __restrict__ out)
{
    int idx = blockIdx.x * 256 + threadIdx.x;      // float4 index; grid covers exactly
    const int PER_B4 = 192 * (HW / 4);             // 442368
    int b = idx / PER_B4;
    int rem = idx - b * PER_B4;
    int ch = rem / (HW / 4);
    int p4 = rem % (HW / 4);
    float4 v;
    if (ch < 128) {
        v = reinterpret_cast<const float4*>(x + ((size_t)b * 128 + ch) * HW)[p4];
    } else {
        int c = ch - 128;
        int pix = p4 * 4;
        int r = pix / 96, cc = pix % 96;           // 4 consecutive pixels share the row (96%4==0)
        float so = So[b * 64 + c], sf = Sf[b * 64 + c];
        float vals[4];
        #pragma unroll
        for (int i = 0; i < 4; ++i) {
            int ccc = cc + i;
            if (r >= 24 && r < 72 && ccc >= 20 && ccc < 68) {
                int m = (r - 24) * 48 + (ccc - 20);
                vals[i] = ori[b * MROWS + m] ? so : sf;
            } else vals[i] = 0.f;
        }
        v = make_float4(vals[0], vals[1], vals[2], vals[3]);
    }
    reinterpret_cast<float4*>(out)[idx] = v;
}

extern "C" void kernel_launch(void* const* d_in, const int* in_sizes, int n_in,
                              void* d_out, int out_size, void* d_ws, size_t ws_size,
                              hipStream_t stream) {
    const float* x    = (const float*)d_in[0];   // [4,128,9216]
    const float* flip = (const float*)d_in[1];   // [4,64,9216]
    char* w = (char*)d_ws;
    float* invnf = (float*)(w + OFF_INVNF);
    float* arro  = (float*)(w + OFF_ARRO);
    float* arrf  = (float*)(w + OFF_ARRF);
    float* pval  = (float*)(w + OFF_PVAL);
    int*   pidx  = (int*)  (w + OFF_PIDX);
    int*   ori   = (int*)  (w + OFF_ORI);
    int*   cfo   = (int*)  (w + OFF_CFO);
    int*   cff   = (int*)  (w + OFF_CFF);
    float* So    = (float*)(w + OFF_SO);
    float* Sf    = (float*)(w + OFF_SF);
    float* out   = (float*)d_out;

    norm_kernel<<<dim3(36, 4), 256, 0, stream>>>(x, flip, invnf, arro, arrf, cfo, cff, So, Sf);
    argmax_kernel<<<dim3(72, 4, 8), 256, 0, stream>>>(x, flip, arro, arrf, pval, pidx);
    merge_kernel<<<36, 256, 0, stream>>>(pval, pidx, invnf, ori, cfo, cff);
    ssum_kernel<<<dim3(8, 64), 256, 0, stream>>>(x, flip, cfo, cff, So, Sf);
    assemble_kernel<<<6912, 256, 0, stream>>>(x, ori, So, Sf, out);
}

// Round 3
// 228.480 us; speedup vs baseline: 3.3638x; 1.9406x over previous
//
#include <hip/hip_runtime.h>
#include <cfloat>
#include <cstddef>

#define HW 9216
#define MROWS 2304
#define STRIPS 8
#define STRIPW 1152   // 9216/8
#define JTILES 9      // 1152/128

typedef _Float16 half8 __attribute__((ext_vector_type(8)));
typedef float f32x16 __attribute__((ext_vector_type(16)));

// ws layout (bytes)
constexpr size_t OFF_INVNF = 0;                       // 4*9216 f32
constexpr size_t OFF_ARRO  = OFF_INVNF + 147456;      // 4*9216 f32 (neg => masked)
constexpr size_t OFF_ARRF  = OFF_ARRO  + 147456;
constexpr size_t OFF_PVAL  = OFF_ARRF  + 147456;      // 8 bb * 8 strips * 2304 f32
constexpr size_t OFF_PIDX  = OFF_PVAL  + 589824;
constexpr size_t OFF_ORI   = OFF_PIDX  + 589824;      // 4*2304 i32
constexpr size_t OFF_CFO   = OFF_ORI   + 36864;       // 4*9216 i32
constexpr size_t OFF_CFF   = OFF_CFO   + 147456;
constexpr size_t OFF_SO    = OFF_CFF   + 147456;      // 4*64 f32
constexpr size_t OFF_SF    = OFF_SO    + 1024;

// K1: per-pixel inverse norms (+mask sign), zero scatter targets
__global__ __launch_bounds__(256) void norm_kernel(
    const float* __restrict__ x, const float* __restrict__ flip,
    float* __restrict__ invnf, float* __restrict__ arro, float* __restrict__ arrf,
    int* __restrict__ cfo, int* __restrict__ cff,
    float* __restrict__ So, float* __restrict__ Sf)
{
    int b = blockIdx.y;
    int pix = blockIdx.x * 256 + threadIdx.x;   // gridDim.x = 36 -> exact
    const float* xb = x + (size_t)b * 128 * HW;
    const float* fb = flip + (size_t)b * 64 * HW;
    float nf = 0.f, nl = 0.f, nfl = 0.f;
    #pragma unroll 8
    for (int c = 0; c < 64; ++c) {
        float a = xb[(size_t)c * HW + pix];        nf  += a * a;
        float l = xb[(size_t)(64 + c) * HW + pix]; nl  += l * l;
        float f = fb[(size_t)c * HW + pix];        nfl += f * f;
    }
    int r = pix / 96, cc = pix % 96;
    bool in_o = (r >= 24 && r < 72 && cc >= 20 && cc < 68);
    bool in_f = (r >= 24 && r < 72 && cc >= 28 && cc < 76);
    float il  = 1.f / sqrtf(nl);
    float ifl = 1.f / sqrtf(nfl);
    invnf[b * HW + pix] = 1.f / sqrtf(nf);
    arro[b * HW + pix] = in_o ? -il  : il;
    arrf[b * HW + pix] = in_f ? -ifl : ifl;
    cfo[b * HW + pix] = 0;
    cff[b * HW + pix] = 0;
    if (pix < 64) { So[b * 64 + pix] = 0.f; Sf[b * 64 + pix] = 0.f; }
}

// K2: MFMA masked-argmax GEMM, fp16 split-3 (hi/lo), 32x32x16_f16.
// grid: x=18 row-blocks(128 m), y=8 j-strips(1152), z=8 (b*2+branch)
__global__ __launch_bounds__(256, 3) void argmax_kernel(
    const float* __restrict__ x, const float* __restrict__ flip,
    const float* __restrict__ arro, const float* __restrict__ arrf,
    float* __restrict__ pval, int* __restrict__ pidx)
{
    int rb = blockIdx.x, strip = blockIdx.y, bb = blockIdx.z;
    int b = bb >> 1, br = bb & 1;
    const float* A  = x + (size_t)b * 128 * HW;                       // former
    const float* Bm = br ? (flip + (size_t)b * 64 * HW)
                         : (x + (size_t)b * 128 * HW + (size_t)64 * HW);
    const float* inv = (br ? arrf : arro) + (size_t)b * HW;
    int cbase = br ? 28 : 20;

    // B fragments in LDS, pre-swizzled: chunk[(ks*2+half)*128 + n] = 8 f16 (k=ks*16+half*8..+7 at col n)
    __shared__ _Float16 Bh[8192];
    __shared__ _Float16 Bl[8192];

    int t = threadIdx.x;
    int lane = t & 63, wv = t >> 6;
    int hf = lane >> 5, l31 = lane & 31;

    // A fragments in registers: lane holds A[m=mbase+l31][k = ks*16 + hf*8 + i]
    int mbase = rb * 128 + wv * 32;
    int m = mbase + l31;
    int pix = (24 + m / 48) * 96 + cbase + (m % 48);
    half8 ahf[4], alf[4];
    #pragma unroll
    for (int ks = 0; ks < 4; ++ks) {
        #pragma unroll
        for (int i = 0; i < 8; ++i) {
            int k = ks * 16 + hf * 8 + i;
            float v = A[(size_t)k * HW + pix];
            _Float16 h = (_Float16)v;
            ahf[ks][i] = h;
            alf[ks][i] = (_Float16)(v - (float)h);
        }
    }

    float rv[16]; int rix[16];
    #pragma unroll
    for (int r = 0; r < 16; ++r) { rv[r] = -FLT_MAX; rix[r] = 0x7fffffff; }

    int jstrip = strip * STRIPW;

    for (int jt = 0; jt < JTILES; ++jt) {
        int jbase = jstrip + jt * 128;
        __syncthreads();
        // stage B tile (64k x 128j) as hi/lo fp16 fragments
        #pragma unroll
        for (int iter = 0; iter < 4; ++iter) {
            int slot = t + iter * 256;
            int j = slot & 127, kseg = slot >> 7;      // kseg = ks*2+half
            const float* p = Bm + (size_t)(kseg * 8) * HW + jbase + j;
            half8 hv, lv;
            #pragma unroll
            for (int i = 0; i < 8; ++i) {
                float v = p[(size_t)i * HW];
                _Float16 h = (_Float16)v;
                hv[i] = h;
                lv[i] = (_Float16)(v - (float)h);
            }
            int chunk = kseg * 128 + j;
            *(half8*)&Bh[chunk * 8] = hv;
            *(half8*)&Bl[chunk * 8] = lv;
        }
        __syncthreads();

        f32x16 acc[4];
        #pragma unroll
        for (int nt = 0; nt < 4; ++nt)
            #pragma unroll
            for (int r = 0; r < 16; ++r) acc[nt][r] = 0.f;

        #pragma unroll
        for (int ks = 0; ks < 4; ++ks) {
            #pragma unroll
            for (int nt = 0; nt < 4; ++nt) {
                int chunk = (ks * 2 + hf) * 128 + nt * 32 + l31;
                half8 bh = *(const half8*)&Bh[chunk * 8];
                half8 bl = *(const half8*)&Bl[chunk * 8];
                acc[nt] = __builtin_amdgcn_mfma_f32_32x32x16_f16(ahf[ks], bh, acc[nt], 0, 0, 0);
                acc[nt] = __builtin_amdgcn_mfma_f32_32x32x16_f16(alf[ks], bh, acc[nt], 0, 0, 0);
                acc[nt] = __builtin_amdgcn_mfma_f32_32x32x16_f16(ahf[ks], bl, acc[nt], 0, 0, 0);
            }
        }

        // epilogue: scale by per-col inv norm (sign=mask), running argmax.
        // C/D layout: col = nt*32 + l31, row = (r&3)+8*(r>>2)+4*hf. Ascending (jt,nt) == ascending j.
        #pragma unroll
        for (int nt = 0; nt < 4; ++nt) {
            int j = jbase + nt * 32 + l31;
            float iv = inv[j];
            bool masked = iv < 0.f;
            #pragma unroll
            for (int r = 0; r < 16; ++r) {
                float s = acc[nt][r] * iv;
                s = masked ? -FLT_MAX : s;
                if (s > rv[r]) { rv[r] = s; rix[r] = j; }
            }
        }
    }

    // cross-lane argmax reduce within each 32-lane half (cols), then write per-row results
    #pragma unroll
    for (int r = 0; r < 16; ++r) {
        float v = rv[r]; int ix = rix[r];
        #pragma unroll
        for (int off = 1; off <= 16; off <<= 1) {
            float ov = __shfl_xor(v, off, 64);
            int   oi = __shfl_xor(ix, off, 64);
            if (ov > v || (ov == v && oi < ix)) { v = ov; ix = oi; }
        }
        if (l31 == 0) {
            int row = (r & 3) + 8 * (r >> 2) + 4 * hf;
            int mm = mbase + row;
            pval[((size_t)bb * STRIPS + strip) * MROWS + mm] = v;
            pidx[((size_t)bb * STRIPS + strip) * MROWS + mm] = ix;
        }
    }
}

// K3: merge 8 strips per (bb,m), compute ori flag, scatter column flags
__global__ __launch_bounds__(256) void merge_kernel(
    const float* __restrict__ pval, const int* __restrict__ pidx,
    const float* __restrict__ invnf, int* __restrict__ ori,
    int* __restrict__ cfo, int* __restrict__ cff)
{
    int gid = blockIdx.x * 256 + threadIdx.x;      // 36 blocks -> 9216 = 4*2304
    int b = gid / MROWS, m = gid % MROWS;
    float bv[2]; int bi[2];
    #pragma unroll
    for (int br = 0; br < 2; ++br) {
        int bb = b * 2 + br;
        float v = -FLT_MAX; int id = 0x7fffffff;
        for (int s = 0; s < STRIPS; ++s) {
            float pv = pval[((size_t)bb * STRIPS + s) * MROWS + m];
            int   pi = pidx[((size_t)bb * STRIPS + s) * MROWS + m];
            if (pv > v || (pv == v && pi < id)) { v = pv; id = pi; }
        }
        int cbase = br ? 28 : 20;
        int pix = (24 + m / 48) * 96 + cbase + (m % 48);
        v *= invnf[b * HW + pix];
        bv[br] = v; bi[br] = id;
    }
    bool o = bv[0] >= bv[1];
    ori[gid] = o ? 1 : 0;
    cfo[b * HW + bi[0]] = 1;
    cff[b * HW + bi[1]] = 1;
}

// K4: S[c] = sum over flagged columns j of Bm[c][j]. One block per (bb, c).
__global__ __launch_bounds__(256) void ssum_kernel(
    const float* __restrict__ x, const float* __restrict__ flip,
    const int* __restrict__ cfo, const int* __restrict__ cff,
    float* __restrict__ So, float* __restrict__ Sf)
{
    int blk = blockIdx.x;                  // 8 = b*2+br
    int c   = blockIdx.y;                  // 64 channels
    int b = blk >> 1, br = blk & 1;
    const float* Bm = br ? (flip + (size_t)b * 64 * HW)
                         : (x + (size_t)b * 128 * HW + (size_t)64 * HW);
    const int* cf = (br ? cff : cfo) + (size_t)b * HW;
    float* S = (br ? Sf : So) + b * 64;

    const float* row = Bm + (size_t)c * HW;
    float acc = 0.f;
    for (int j = threadIdx.x; j < HW; j += 256) {
        if (cf[j]) acc += row[j];
    }
    for (int off = 32; off > 0; off >>= 1) acc += __shfl_down(acc, off, 64);
    __shared__ float part[4];
    int lane = threadIdx.x & 63, w = threadIdx.x >> 6;
    if (lane == 0) part[w] = acc;
    __syncthreads();
    if (threadIdx.x == 0) S[c] = part[0] + part[1] + part[2] + part[3];
}

// K5: assemble output [4][192][9216]
__global__ __launch_bounds__(256) void assemble_kernel(
    const float* __restrict__ x, const int* __restrict__ ori,
    const float* __restrict__ So, const float* __restrict__ Sf,
    float* __restrict__ out)
{
    int idx = blockIdx.x * 256 + threadIdx.x;      // float4 index; grid covers exactly
    const int PER_B4 = 192 * (HW / 4);             // 442368
    int b = idx / PER_B4;
    int rem = idx - b * PER_B4;
    int ch = rem / (HW / 4);
    int p4 = rem % (HW / 4);
    float4 v;
    if (ch < 128) {
        v = reinterpret_cast<const float4*>(x + ((size_t)b * 128 + ch) * HW)[p4];
    } else {
        int c = ch - 128;
        int pix = p4 * 4;
        int r = pix / 96, cc = pix % 96;           // 4 consecutive pixels share the row (96%4==0)
        float so = So[b * 64 + c], sf = Sf[b * 64 + c];
        float vals[4];
        #pragma unroll
        for (int i = 0; i < 4; ++i) {
            int ccc = cc + i;
            if (r >= 24 && r < 72 && ccc >= 20 && ccc < 68) {
                int mm = (r - 24) * 48 + (ccc - 20);
                vals[i] = ori[b * MROWS + mm] ? so : sf;
            } else vals[i] = 0.f;
        }
        v = make_float4(vals[0], vals[1], vals[2], vals[3]);
    }
    reinterpret_cast<float4*>(out)[idx] = v;
}

extern "C" void kernel_launch(void* const* d_in, const int* in_sizes, int n_in,
                              void* d_out, int out_size, void* d_ws, size_t ws_size,
                              hipStream_t stream) {
    const float* x    = (const float*)d_in[0];   // [4,128,9216]
    const float* flip = (const float*)d_in[1];   // [4,64,9216]
    char* w = (char*)d_ws;
    float* invnf = (float*)(w + OFF_INVNF);
    float* arro  = (float*)(w + OFF_ARRO);
    float* arrf  = (float*)(w + OFF_ARRF);
    float* pval  = (float*)(w + OFF_PVAL);
    int*   pidx  = (int*)  (w + OFF_PIDX);
    int*   ori   = (int*)  (w + OFF_ORI);
    int*   cfo   = (int*)  (w + OFF_CFO);
    int*   cff   = (int*)  (w + OFF_CFF);
    float* So    = (float*)(w + OFF_SO);
    float* Sf    = (float*)(w + OFF_SF);
    float* out   = (float*)d_out;

    norm_kernel<<<dim3(36, 4), 256, 0, stream>>>(x, flip, invnf, arro, arrf, cfo, cff, So, Sf);
    argmax_kernel<<<dim3(18, 8, 8), 256, 0, stream>>>(x, flip, arro, arrf, pval, pidx);
    merge_kernel<<<36, 256, 0, stream>>>(pval, pidx, invnf, ori, cfo, cff);
    ssum_kernel<<<dim3(8, 64), 256, 0, stream>>>(x, flip, cfo, cff, So, Sf);
    assemble_kernel<<<6912, 256, 0, stream>>>(x, ori, So, Sf, out);
}

// Round 4
// 215.695 us; speedup vs baseline: 3.5632x; 1.0593x over previous
//
#include <hip/hip_runtime.h>
#include <cfloat>
#include <cstddef>
#include <cstdint>

#define HW 9216
#define MROWS 2304
#define STRIPS 8
#define STRIPW 1152   // 9216/8
#define JTILES 9      // 1152/128

typedef _Float16 half8 __attribute__((ext_vector_type(8)));
typedef float f32x16 __attribute__((ext_vector_type(16)));

// bpack: [2 dtype(hi/lo)][8 bb][8 kseg][9216 j] chunks of 8 halves (16 B)
constexpr size_t BP_CHUNKS_PER_DTYPE = 8ull * 8 * HW;       // 589824 chunks
constexpr size_t OFF_BPACK = 0;                             // 2*589824*16 = 18,874,368 B
constexpr size_t OFF_PVAL  = OFF_BPACK + 2 * BP_CHUNKS_PER_DTYPE * 16;
constexpr size_t OFF_PIDX  = OFF_PVAL + 589824;             // 8bb*8strips*2304 f32
constexpr size_t OFF_ORI   = OFF_PIDX + 589824;
constexpr size_t OFF_CFO   = OFF_ORI  + 36864;
constexpr size_t OFF_CFF   = OFF_CFO  + 147456;
constexpr size_t OFF_SO    = OFF_CFF  + 147456;
constexpr size_t OFF_SF    = OFF_SO   + 1024;

// K0: pre-scale B columns by 1/|b| (NaN for masked cols), split fp16 hi/lo,
// write in MFMA fragment order. Also zero the column-flag scatter targets.
__global__ __launch_bounds__(256) void pack_kernel(
    const float* __restrict__ x, const float* __restrict__ flip,
    _Float16* __restrict__ bpack, int* __restrict__ cfo, int* __restrict__ cff)
{
    int bb = blockIdx.y;                 // b*2+br
    int b = bb >> 1, br = bb & 1;
    int j = blockIdx.x * 256 + threadIdx.x;   // gridDim.x=36 -> exact
    const float* Bm = br ? (flip + (size_t)b * 64 * HW)
                         : (x + (size_t)b * 128 * HW + (size_t)64 * HW);
    float v[64];
    float norm = 0.f;
    #pragma unroll 16
    for (int k = 0; k < 64; ++k) {
        float a = Bm[(size_t)k * HW + j];
        v[k] = a;
        norm += a * a;
    }
    int r = j / 96, cc = j % 96;
    int cb = br ? 28 : 20;
    bool masked = (r >= 24 && r < 72 && cc >= cb && cc < cb + 48);
    float iv = 1.f / sqrtf(norm);
    if (masked) iv = __builtin_nanf("");

    half8* bp = (half8*)bpack;
    #pragma unroll
    for (int kseg = 0; kseg < 8; ++kseg) {
        half8 hv, lv;
        #pragma unroll
        for (int i = 0; i < 8; ++i) {
            float s = v[kseg * 8 + i] * iv;
            _Float16 h = (_Float16)s;
            hv[i] = h;
            lv[i] = (_Float16)(s - (float)h);
        }
        size_t chunk = ((size_t)bb * 8 + kseg) * HW + j;
        bp[chunk] = hv;
        bp[chunk + BP_CHUNKS_PER_DTYPE] = lv;
    }
    if (br == 0) cfo[b * HW + j] = 0;
    else         cff[b * HW + j] = 0;
}

// K1: MFMA masked-argmax GEMM, fp16 split-3, 32x32x16_f16.
// grid: x=18 row-blocks(128 m), y=8 j-strips(1152), z=8 (b*2+branch)
__global__ __launch_bounds__(256, 3) void argmax_kernel(
    const float* __restrict__ x, const _Float16* __restrict__ bpack,
    float* __restrict__ pval, int* __restrict__ pidx)
{
    int rb = blockIdx.x, strip = blockIdx.y, bb = blockIdx.z;
    int b = bb >> 1, br = bb & 1;
    const float* A = x + (size_t)b * 128 * HW;     // former
    int cbase = br ? 28 : 20;

    __shared__ _Float16 BB[16384];   // [2 dtype][8 kseg][128 j][8 halves] = 32 KB

    int t = threadIdx.x, lane = t & 63, wv = t >> 6;
    int hf = lane >> 5, l31 = lane & 31;

    // A fragments: lane holds A[m=mbase+l31][k=ks*16+hf*8+i]
    int mbase = rb * 128 + wv * 32;
    int m = mbase + l31;
    int pix = (24 + m / 48) * 96 + cbase + (m % 48);
    half8 ahf[4], alf[4];
    #pragma unroll
    for (int ks = 0; ks < 4; ++ks) {
        #pragma unroll
        for (int i = 0; i < 8; ++i) {
            int k = ks * 16 + hf * 8 + i;
            float v = A[(size_t)k * HW + pix];
            _Float16 h = (_Float16)v;
            ahf[ks][i] = h;
            alf[ks][i] = (_Float16)(v - (float)h);
        }
    }

    float rv[16]; int rix[16];
    #pragma unroll
    for (int r = 0; r < 16; ++r) { rv[r] = -FLT_MAX; rix[r] = 0x7fffffff; }

    const half8* bp  = (const half8*)bpack;
    const half8* bb8 = (const half8*)BB;
    int jstrip = strip * STRIPW;

    for (int jt = 0; jt < JTILES; ++jt) {
        int jbase = jstrip + jt * 128;
        __syncthreads();
        // stage 32 KB via direct global->LDS DMA: 32 regions of 64 chunks (1 KB), 8/wave
        #pragma unroll
        for (int i = 0; i < 8; ++i) {
            int reg = wv * 8 + i;
            int dtype = reg >> 4, kseg = (reg >> 1) & 7, jh = reg & 1;
            size_t gchunk = (size_t)dtype * BP_CHUNKS_PER_DTYPE
                          + ((size_t)bb * 8 + kseg) * HW + jbase + jh * 64 + lane;
            uint32_t ldsoff = (uint32_t)(((dtype * 8 + kseg) * 128 + jh * 64) * 16);
            __builtin_amdgcn_global_load_lds(
                (const __attribute__((address_space(1))) void*)(bp + gchunk),
                (__attribute__((address_space(3))) void*)((char*)BB + ldsoff),
                16, 0, 0);
        }
        __syncthreads();

        f32x16 acc[4];
        #pragma unroll
        for (int nt = 0; nt < 4; ++nt)
            #pragma unroll
            for (int r = 0; r < 16; ++r) acc[nt][r] = 0.f;

        #pragma unroll
        for (int ks = 0; ks < 4; ++ks) {
            int kseg = ks * 2 + hf;
            #pragma unroll
            for (int nt = 0; nt < 4; ++nt) {
                half8 bh = bb8[kseg * 128 + nt * 32 + l31];
                half8 bl = bb8[(8 + kseg) * 128 + nt * 32 + l31];
                acc[nt] = __builtin_amdgcn_mfma_f32_32x32x16_f16(ahf[ks], bh, acc[nt], 0, 0, 0);
                acc[nt] = __builtin_amdgcn_mfma_f32_32x32x16_f16(alf[ks], bh, acc[nt], 0, 0, 0);
                acc[nt] = __builtin_amdgcn_mfma_f32_32x32x16_f16(ahf[ks], bl, acc[nt], 0, 0, 0);
            }
        }

        // epilogue: scores are pre-scaled; masked cols are NaN (never selected by >)
        #pragma unroll
        for (int nt = 0; nt < 4; ++nt) {
            int j = jbase + nt * 32 + l31;
            #pragma unroll
            for (int r = 0; r < 16; ++r) {
                float s = acc[nt][r];
                if (s > rv[r]) { rv[r] = s; rix[r] = j; }
            }
        }
    }

    // cross-lane argmax reduce within each 32-lane half (cols), write per-row results
    #pragma unroll
    for (int r = 0; r < 16; ++r) {
        float v = rv[r]; int ix = rix[r];
        #pragma unroll
        for (int off = 1; off <= 16; off <<= 1) {
            float ov = __shfl_xor(v, off, 64);
            int   oi = __shfl_xor(ix, off, 64);
            if (ov > v || (ov == v && oi < ix)) { v = ov; ix = oi; }
        }
        if (l31 == 0) {
            int row = (r & 3) + 8 * (r >> 2) + 4 * hf;
            int mm = mbase + row;
            pval[((size_t)bb * STRIPS + strip) * MROWS + mm] = v;
            pidx[((size_t)bb * STRIPS + strip) * MROWS + mm] = ix;
        }
    }
}

// K2: merge 8 strips per (bb,m), apply 1/|a| (computed inline), ori flag, scatter col flags
__global__ __launch_bounds__(256) void merge_kernel(
    const float* __restrict__ pval, const int* __restrict__ pidx,
    const float* __restrict__ x, int* __restrict__ ori,
    int* __restrict__ cfo, int* __restrict__ cff)
{
    int gid = blockIdx.x * 256 + threadIdx.x;      // 36 blocks -> 9216 = 4*2304
    int b = gid / MROWS, m = gid % MROWS;
    float bv[2]; int bi[2];
    #pragma unroll
    for (int br = 0; br < 2; ++br) {
        int bb = b * 2 + br;
        float v = -FLT_MAX; int id = 0x7fffffff;
        #pragma unroll
        for (int s = 0; s < STRIPS; ++s) {
            float pv = pval[((size_t)bb * STRIPS + s) * MROWS + m];
            int   pi = pidx[((size_t)bb * STRIPS + s) * MROWS + m];
            if (pv > v || (pv == v && pi < id)) { v = pv; id = pi; }
        }
        bv[br] = v; bi[br] = id;
    }
    // inline former-norms at both branch pixels
    const float* xb = x + (size_t)b * 128 * HW;
    int row = 24 + m / 48, col = m % 48;
    int pix0 = row * 96 + 20 + col;
    int pix1 = row * 96 + 28 + col;
    float nf0 = 0.f, nf1 = 0.f;
    #pragma unroll 8
    for (int k = 0; k < 64; ++k) {
        float a0 = xb[(size_t)k * HW + pix0]; nf0 += a0 * a0;
        float a1 = xb[(size_t)k * HW + pix1]; nf1 += a1 * a1;
    }
    bv[0] *= 1.f / sqrtf(nf0);
    bv[1] *= 1.f / sqrtf(nf1);

    bool o = bv[0] >= bv[1];
    ori[gid] = o ? 1 : 0;
    cfo[b * HW + bi[0]] = 1;
    cff[b * HW + bi[1]] = 1;
}

// K3: S[c] = sum over flagged columns j of Bm[c][j]. One block per (bb, c).
__global__ __launch_bounds__(256) void ssum_kernel(
    const float* __restrict__ x, const float* __restrict__ flip,
    const int* __restrict__ cfo, const int* __restrict__ cff,
    float* __restrict__ So, float* __restrict__ Sf)
{
    int blk = blockIdx.x;                  // 8 = b*2+br
    int c   = blockIdx.y;                  // 64 channels
    int b = blk >> 1, br = blk & 1;
    const float* Bm = br ? (flip + (size_t)b * 64 * HW)
                         : (x + (size_t)b * 128 * HW + (size_t)64 * HW);
    const int* cf = (br ? cff : cfo) + (size_t)b * HW;
    float* S = (br ? Sf : So) + b * 64;

    const float* row = Bm + (size_t)c * HW;
    float acc = 0.f;
    for (int j = threadIdx.x; j < HW; j += 256) {
        if (cf[j]) acc += row[j];
    }
    for (int off = 32; off > 0; off >>= 1) acc += __shfl_down(acc, off, 64);
    __shared__ float part[4];
    int lane = threadIdx.x & 63, w = threadIdx.x >> 6;
    if (lane == 0) part[w] = acc;
    __syncthreads();
    if (threadIdx.x == 0) S[c] = part[0] + part[1] + part[2] + part[3];
}

// K4: assemble output [4][192][9216]
__global__ __launch_bounds__(256) void assemble_kernel(
    const float* __restrict__ x, const int* __restrict__ ori,
    const float* __restrict__ So, const float* __restrict__ Sf,
    float* __restrict__ out)
{
    int idx = blockIdx.x * 256 + threadIdx.x;      // float4 index; grid covers exactly
    const int PER_B4 = 192 * (HW / 4);             // 442368
    int b = idx / PER_B4;
    int rem = idx - b * PER_B4;
    int ch = rem / (HW / 4);
    int p4 = rem % (HW / 4);
    float4 v;
    if (ch < 128) {
        v = reinterpret_cast<const float4*>(x + ((size_t)b * 128 + ch) * HW)[p4];
    } else {
        int c = ch - 128;
        int pix = p4 * 4;
        int r = pix / 96, cc = pix % 96;           // 4 consecutive pixels share the row (96%4==0)
        float so = So[b * 64 + c], sf = Sf[b * 64 + c];
        float vals[4];
        #pragma unroll
        for (int i = 0; i < 4; ++i) {
            int ccc = cc + i;
            if (r >= 24 && r < 72 && ccc >= 20 && ccc < 68) {
                int mm = (r - 24) * 48 + (ccc - 20);
                vals[i] = ori[b * MROWS + mm] ? so : sf;
            } else vals[i] = 0.f;
        }
        v = make_float4(vals[0], vals[1], vals[2], vals[3]);
    }
    reinterpret_cast<float4*>(out)[idx] = v;
}

extern "C" void kernel_launch(void* const* d_in, const int* in_sizes, int n_in,
                              void* d_out, int out_size, void* d_ws, size_t ws_size,
                              hipStream_t stream) {
    const float* x    = (const float*)d_in[0];   // [4,128,9216]
    const float* flip = (const float*)d_in[1];   // [4,64,9216]
    char* w = (char*)d_ws;
    _Float16* bpack = (_Float16*)(w + OFF_BPACK);
    float* pval  = (float*)(w + OFF_PVAL);
    int*   pidx  = (int*)  (w + OFF_PIDX);
    int*   ori   = (int*)  (w + OFF_ORI);
    int*   cfo   = (int*)  (w + OFF_CFO);
    int*   cff   = (int*)  (w + OFF_CFF);
    float* So    = (float*)(w + OFF_SO);
    float* Sf    = (float*)(w + OFF_SF);
    float* out   = (float*)d_out;

    pack_kernel<<<dim3(36, 8), 256, 0, stream>>>(x, flip, bpack, cfo, cff);
    argmax_kernel<<<dim3(18, 8, 8), 256, 0, stream>>>(x, bpack, pval, pidx);
    merge_kernel<<<36, 256, 0, stream>>>(pval, pidx, x, ori, cfo, cff);
    ssum_kernel<<<dim3(8, 64), 256, 0, stream>>>(x, flip, cfo, cff, So, Sf);
    assemble_kernel<<<6912, 256, 0, stream>>>(x, ori, So, Sf, out);
}